// Round 1
// 1117.228 us; speedup vs baseline: 1.0168x; 1.0168x over previous
//
#include <hip/hip_runtime.h>
#include <hip/hip_bf16.h>

typedef __bf16 v8bf __attribute__((ext_vector_type(8)));
typedef __bf16 v4bf __attribute__((ext_vector_type(4)));
typedef float  v4f  __attribute__((ext_vector_type(4)));

__device__ __forceinline__ v8bf zero8() {
    v8bf r;
#pragma unroll
    for (int i = 0; i < 8; ++i) r[i] = (__bf16)0.f;
    return r;
}
__device__ __forceinline__ v4f zero4() { v4f r; r[0]=r[1]=r[2]=r[3]=0.f; return r; }

__device__ __forceinline__ v8bf load8bf(const __bf16* p) { return *(const v8bf*)p; }

__device__ __forceinline__ v8bf load8f(const float* p) {
    const float4 x = ((const float4*)p)[0];
    const float4 y = ((const float4*)p)[1];
    v8bf r;
    r[0]=(__bf16)x.x; r[1]=(__bf16)x.y; r[2]=(__bf16)x.z; r[3]=(__bf16)x.w;
    r[4]=(__bf16)y.x; r[5]=(__bf16)y.y; r[6]=(__bf16)y.z; r[7]=(__bf16)y.w;
    return r;
}
__device__ __forceinline__ float silu_f(float x) { return x / (1.f + __expf(-x)); }

// ---------------- fused weight transposes: fp32 [K][N] -> bf16 [N][K] ----------------
struct TDesc { const float* s; __bf16* d; int K; int N; };
struct TPack { TDesc t[9]; };

__global__ __launch_bounds__(256) void transpose_all(TPack p) {
    TDesc td = p.t[blockIdx.x];
    int total = td.K * td.N;
    for (int idx = blockIdx.y * 256 + threadIdx.x; idx < total; idx += 16 * 256) {
        int k = idx / td.N, n = idx - k * td.N;
        td.d[n * td.K + k] = (__bf16)td.s[idx];
    }
}

// ================= CSR construction (counting sort by destination) =================
// Both graphs processed in ONE pipeline: counts2 == counts + N, partials has 2*nbS slots.
__global__ __launch_bounds__(256) void hist_both(const int* __restrict__ idxE,
                                                 const int* __restrict__ idxH,
                                                 int* __restrict__ countsE,
                                                 int* __restrict__ countsH,
                                                 int E, int EH) {
    int g = blockIdx.x * 256 + threadIdx.x;
    if (g < E) atomicAdd(&countsE[idxE[g]], 1);
    else if (g < E + EH) atomicAdd(&countsH[idxH[g - E]], 1);
}

__global__ __launch_bounds__(256) void scan_block_sums(const int* __restrict__ counts,
                                                       int* __restrict__ partials,
                                                       int n, int nbS) {
    int t = threadIdx.x, b = blockIdx.x;
    const int* src = counts + ((b >= nbS) ? n : 0);
    int bb = (b >= nbS) ? b - nbS : b;
    int base = bb * 2048 + t * 8;
    int s = 0;
#pragma unroll
    for (int i = 0; i < 8; ++i) {
        int g = base + i;
        s += (g < n) ? src[g] : 0;
    }
#pragma unroll
    for (int off = 32; off; off >>= 1) s += __shfl_down(s, off);
    __shared__ int wsum[4];
    if ((t & 63) == 0) wsum[t >> 6] = s;
    __syncthreads();
    if (t == 0) partials[b] = wsum[0] + wsum[1] + wsum[2] + wsum[3];
}

// parallel exclusive scan of both partial arrays (wave 0: main, wave 1: hull)
__global__ void scan_partials_two(int* __restrict__ partials, int nb,
                                  int* __restrict__ row_s, int* __restrict__ row2,
                                  int N, int E, int EH) {
    int w = threadIdx.x >> 6, lane = threadIdx.x & 63;
    if (w > 1) return;
    int* p = partials + w * nb;
    if (nb <= 64) {
        int v = (lane < nb) ? p[lane] : 0;
        int orig = v;
#pragma unroll
        for (int d = 1; d < 64; d <<= 1) {
            int u = __shfl_up(v, d);
            if (lane >= d) v += u;
        }
        if (lane < nb) p[lane] = v - orig;
    } else if (lane == 0) {
        int run = 0;
        for (int i = 0; i < nb; ++i) { int tv = p[i]; p[i] = run; run += tv; }
    }
    if (lane == 0) { if (w == 0) row_s[N] = E; else row2[N] = EH; }
}

__global__ __launch_bounds__(256) void scan_write(const int* __restrict__ counts,
                                                  const int* __restrict__ partials,
                                                  int* __restrict__ row_s,
                                                  int* __restrict__ cursor,
                                                  int* __restrict__ row2,
                                                  int* __restrict__ cursor2,
                                                  int n, int nbS) {
    int t = threadIdx.x, b = blockIdx.x;
    bool hull = b >= nbS;
    const int* src = counts + (hull ? n : 0);
    int bb = hull ? b - nbS : b;
    int* rs = hull ? row2 : row_s;
    int* cu = hull ? cursor2 : cursor;
    int base = bb * 2048 + t * 8;
    int vals[8];
    int tot = 0;
#pragma unroll
    for (int i = 0; i < 8; ++i) {
        int g = base + i;
        vals[i] = (g < n) ? src[g] : 0;
        tot += vals[i];
    }
    __shared__ int sh[256];
    sh[t] = tot;
    __syncthreads();
#pragma unroll
    for (int d = 1; d < 256; d <<= 1) {
        int v = (t >= d) ? sh[t - d] : 0;
        __syncthreads();
        sh[t] += v;
        __syncthreads();
    }
    int run = partials[b] + sh[t] - tot;
#pragma unroll
    for (int i = 0; i < 8; ++i) {
        int g = base + i;
        if (g < n) { rs[g] = run; cu[g] = run; }
        run += vals[i];
    }
}

__global__ __launch_bounds__(256) void rank_scatter_both(const int* __restrict__ idxE,
                                                         const int* __restrict__ idxH,
                                                         int* __restrict__ cursorE,
                                                         int* __restrict__ cursorH,
                                                         int* __restrict__ order,
                                                         int* __restrict__ perm2,
                                                         int* __restrict__ dests2,
                                                         int E, int EH) {
    int g = blockIdx.x * 256 + threadIdx.x;
    if (g < E) {
        int d = idxE[g];
        int pos = atomicAdd(&cursorE[d], 1);
        order[pos] = g;
    } else if (g < E + EH) {
        int e = g - E;
        int d = idxH[e];
        int pos = atomicAdd(&cursorH[d], 1);
        perm2[pos] = e;
        dests2[pos] = d;
    }
}

// ===== gather-reduce v2: half-block/node, 4 edge-groups x 32 lanes x float4 =====
__global__ __launch_bounds__(256) void gather_v(const float* __restrict__ e2,
                                                const int* __restrict__ order,
                                                const int* __restrict__ row_start,
                                                __bf16* __restrict__ v, int N) {
    __shared__ float4 red[2][4][32];
    int t = threadIdx.x;
    int half = t >> 7, tl = t & 127;
    int grp = tl >> 5, lane = tl & 31;
    int node = blockIdx.x * 2 + half;
    int nc = (node < N) ? node : N - 1;
    int r0 = row_start[nc], r1 = row_start[nc + 1];
    float4 acc = make_float4(0.f, 0.f, 0.f, 0.f);
    int r = r0 + grp;
    for (; r + 4 < r1; r += 8) {   // 2 independent loads in flight per group
        int e0 = order[r], e1 = order[r + 4];
        float4 a = *(const float4*)(e2 + (size_t)e0 * 128 + lane * 4);
        float4 b = *(const float4*)(e2 + (size_t)e1 * 128 + lane * 4);
        acc.x += a.x + b.x; acc.y += a.y + b.y;
        acc.z += a.z + b.z; acc.w += a.w + b.w;
    }
    if (r < r1) {
        int e0 = order[r];
        float4 a = *(const float4*)(e2 + (size_t)e0 * 128 + lane * 4);
        acc.x += a.x; acc.y += a.y; acc.z += a.z; acc.w += a.w;
    }
    red[half][grp][lane] = acc;
    __syncthreads();
    if (grp == 0 && node < N) {
        float4 s0 = red[half][0][lane], s1 = red[half][1][lane];
        float4 s2 = red[half][2][lane], s3 = red[half][3][lane];
        v4bf o;
        o[0] = (__bf16)(s0.x + s1.x + s2.x + s3.x);
        o[1] = (__bf16)(s0.y + s1.y + s2.y + s3.y);
        o[2] = (__bf16)(s0.z + s1.z + s2.z + s3.z);
        o[3] = (__bf16)(s0.w + s1.w + s2.w + s3.w);
        *(v4bf*)(v + (size_t)node * 128 + lane * 4) = o;
    }
}

// ---------------- v_hull = v @ w_hull  [M,128]x[128,128], B in LDS ----------------
__global__ __launch_bounds__(256) void gemm_vhull(const __bf16* __restrict__ v,
                                                  const __bf16* __restrict__ wT,
                                                  __bf16* __restrict__ out, int M) {
    __shared__ __bf16 bS[128 * 136];
    int t = threadIdx.x, wave = t >> 6, lane = t & 63, q = lane >> 4, l16 = lane & 15;
    int m0 = blockIdx.x * 128;
    {
        int row = t >> 1, half = t & 1;
        const v8bf* g = (const v8bf*)(wT + (size_t)row * 128 + half * 64);
        v8bf* d = (v8bf*)(bS + row * 136 + half * 64);
#pragma unroll
        for (int i = 0; i < 8; ++i) d[i] = g[i];
    }
    __syncthreads();
    int r0 = m0 + wave * 32;
    v4f acc[2][8];
#pragma unroll
    for (int i = 0; i < 2; ++i)
#pragma unroll
        for (int j = 0; j < 8; ++j) acc[i][j] = zero4();
    int ar0 = r0 + l16;      if (ar0 >= M) ar0 = M - 1;
    int ar1 = r0 + 16 + l16; if (ar1 >= M) ar1 = M - 1;
#pragma unroll
    for (int kt = 0; kt < 4; ++kt) {
        v8bf a0 = load8bf(v + (size_t)ar0 * 128 + kt * 32 + q * 8);
        v8bf a1 = load8bf(v + (size_t)ar1 * 128 + kt * 32 + q * 8);
#pragma unroll
        for (int nt = 0; nt < 8; ++nt) {
            v8bf b = *(const v8bf*)(bS + (nt * 16 + l16) * 136 + kt * 32 + q * 8);
            acc[0][nt] = __builtin_amdgcn_mfma_f32_16x16x32_bf16(a0, b, acc[0][nt], 0, 0, 0);
            acc[1][nt] = __builtin_amdgcn_mfma_f32_16x16x32_bf16(a1, b, acc[1][nt], 0, 0, 0);
        }
    }
#pragma unroll
    for (int tile = 0; tile < 2; ++tile)
#pragma unroll
        for (int nt = 0; nt < 8; ++nt)
#pragma unroll
            for (int r = 0; r < 4; ++r) {
                int row = r0 + tile * 16 + q * 4 + r;
                if (row < M) out[(size_t)row * 128 + nt * 16 + l16] = (__bf16)acc[tile][nt][r];
            }
}

// -------- hull messages FUSED with destination segment-sum (CSR-ordered slots) --------
// Computes msg[slot] = vhull[j]*Wh in LDS, then in-block segment reduction over the
// (contiguous) destination runs, flushed with f32 atomics into oh32. No msg buffer.
__global__ __launch_bounds__(256) void hull_msg(const float* __restrict__ fea,
                                                const int* __restrict__ perm,
                                                const int* __restrict__ jidx,
                                                const int* __restrict__ dests,
                                                const __bf16* __restrict__ w0T,
                                                const float* __restrict__ bias0,
                                                const __bf16* __restrict__ w1T,
                                                const float* __restrict__ bias1,
                                                const __bf16* __restrict__ vhull,
                                                float* __restrict__ oh32, int EH) {
    __shared__ __bf16 hb[64][136];
    __shared__ __bf16 whS[64][136];
    __shared__ int jb[64];
    __shared__ int db[64];
    int t = threadIdx.x;
    int wave = t >> 6, lane = t & 63, q = lane >> 4, l16 = lane & 15;
    int r0 = blockIdx.x * 64;
    if (t < 64) {
        int slot = r0 + t;
        int sc = (slot < EH) ? slot : EH - 1;
        jb[t] = jidx[perm[sc]];
        db[t] = (slot < EH) ? dests[slot] : -1;
    }
    {   // stage 1: h = silu(fea[e] @ w_mlp0 + b0), K=16 padded
        int slot = r0 + wave * 16 + l16; if (slot >= EH) slot = EH - 1;
        int e = perm[slot];
        v8bf a = (q < 2) ? load8f(fea + (size_t)e * 16 + q * 8) : zero8();
        v4f acc[8];
#pragma unroll
        for (int i = 0; i < 8; ++i) acc[i] = zero4();
#pragma unroll
        for (int nt = 0; nt < 8; ++nt) {
            v8bf b = (q < 2) ? load8bf(w0T + (size_t)(nt * 16 + l16) * 16 + q * 8) : zero8();
            acc[nt] = __builtin_amdgcn_mfma_f32_16x16x32_bf16(a, b, acc[nt], 0, 0, 0);
        }
#pragma unroll
        for (int nt = 0; nt < 8; ++nt) {
            int col = nt * 16 + l16;
            float bc = bias0[col];
#pragma unroll
            for (int r = 0; r < 4; ++r) {
                int rowL = wave * 16 + q * 4 + r;
                hb[rowL][col] = (__bf16)silu_f(acc[nt][r] + bc);
            }
        }
    }
    __syncthreads();
    {   // stage 2: Wh = h @ w_mlp1 + b1 -> whS
        v8bf af[4];
#pragma unroll
        for (int kt = 0; kt < 4; ++kt)
            af[kt] = *(const v8bf*)&hb[wave * 16 + l16][kt * 32 + q * 8];
        v4f acc[8];
#pragma unroll
        for (int i = 0; i < 8; ++i) acc[i] = zero4();
#pragma unroll
        for (int kt = 0; kt < 4; ++kt)
#pragma unroll
            for (int nt = 0; nt < 8; ++nt) {
                v8bf b = load8bf(w1T + (size_t)(nt * 16 + l16) * 128 + kt * 32 + q * 8);
                acc[nt] = __builtin_amdgcn_mfma_f32_16x16x32_bf16(af[kt], b, acc[nt], 0, 0, 0);
            }
#pragma unroll
        for (int nt = 0; nt < 8; ++nt) {
            int col = nt * 16 + l16;
            float bc = bias1[col];
#pragma unroll
            for (int r = 0; r < 4; ++r) {
                int rowL = wave * 16 + q * 4 + r;
                whS[rowL][col] = (__bf16)(acc[nt][r] + bc);
            }
        }
    }
    __syncthreads();
    {   // phase A: product in place: whS[row][:] *= vhull[jb[row]][:]
        int row = t >> 2, sub = t & 3;
        int slot = r0 + row;
        if (slot < EH) {
            int j = jb[row];
            const v8bf* vr = (const v8bf*)(vhull + (size_t)j * 128 + sub * 32);
#pragma unroll
            for (int i = 0; i < 4; ++i) {
                v8bf wv = *(const v8bf*)&whS[row][sub * 32 + i * 8];
                v8bf vv = vr[i];
                v8bf o;
#pragma unroll
                for (int k = 0; k < 8; ++k) o[k] = (__bf16)((float)wv[k] * (float)vv[k]);
                *(v8bf*)&whS[row][sub * 32 + i * 8] = o;
            }
        }
    }
    __syncthreads();
    {   // phase B: per-column segment-sum over destination runs; atomic flush.
        // 2 threads/col: halves [0,32) and [32,64). Dest runs are contiguous (CSR order),
        // branch is wave-uniform (all lanes in a wave share the same row sequence).
        int c = t & 127, half = t >> 7;
        int rbeg = half * 32, rend = rbeg + 32;
        float run = 0.f; int cur = -1;
        for (int r = rbeg; r < rend; ++r) {
            int d = db[r];
            if (d != cur) {
                if (cur >= 0) atomicAdd(oh32 + (size_t)cur * 128 + c, run);
                run = 0.f; cur = d;
            }
            if (cur >= 0) run += (float)whS[r][c];
        }
        if (cur >= 0) atomicAdd(oh32 + (size_t)cur * 128 + c, run);
    }
}

// ================= fused per-node MLP chain v3: 512 threads, 8 waves =================
// 128 rows/block, 16 rows/wave (wave owns rows: no act barriers).
// B-chunk staging is register-prefetched: next chunk's global loads are issued before
// the MFMA of the current chunk; the pre-MFMA barrier is a RAW s_barrier with manual
// lgkmcnt(0) so the prefetch vmcnt stays outstanding across it (hidden under MFMA).
#define ALD 392
#define BLD 392

template<int K, int NCH, bool SILU>
__device__ __forceinline__ void gemm_stage(const __bf16* __restrict__ wT,
                                           const float* __restrict__ bias,
                                           __bf16* actS, __bf16* bS,
                                           int srcCol, int dstCol,
                                           int wave, int lane, int t) {
    int q = lane >> 4, l16 = lane & 15;
    v4f acc[NCH * 4];
#pragma unroll
    for (int j = 0; j < NCH * 4; ++j) acc[j] = zero4();

    int brow = t >> 3, sub = t & 7;   // 8 threads per B row (64 rows/chunk)
    constexpr int RV = K / 64;        // v8bf per thread per chunk
    v8bf breg[RV];
    {   // preload chunk 0
        const v8bf* g = (const v8bf*)(wT + (size_t)brow * K) + sub * RV;
#pragma unroll
        for (int i = 0; i < RV; ++i) breg[i] = g[i];
    }
#pragma unroll
    for (int c = 0; c < NCH; ++c) {
        __syncthreads();              // all waves done reading bS (prev chunk / prev stage)
        {
            v8bf* d = (v8bf*)(bS + brow * BLD) + sub * RV;
#pragma unroll
            for (int i = 0; i < RV; ++i) d[i] = breg[i];
        }
        if (c + 1 < NCH) {            // issue next chunk's loads: in flight across barrier+MFMA
            const v8bf* g = (const v8bf*)(wT + (size_t)((c + 1) * 64 + brow) * K) + sub * RV;
#pragma unroll
            for (int i = 0; i < RV; ++i) breg[i] = g[i];
        }
        asm volatile("s_waitcnt lgkmcnt(0)" ::: "memory");   // ds_writes visible
        __builtin_amdgcn_s_barrier();                        // no vmcnt drain
        __builtin_amdgcn_sched_barrier(0);
#pragma unroll
        for (int kt = 0; kt < K / 32; ++kt) {
            v8bf a0 = *(const v8bf*)(actS + (wave * 16 + l16) * ALD + srcCol + kt * 32 + q * 8);
#pragma unroll
            for (int nt = 0; nt < 4; ++nt) {
                v8bf b = *(const v8bf*)(bS + (nt * 16 + l16) * BLD + kt * 32 + q * 8);
                acc[c * 4 + nt] = __builtin_amdgcn_mfma_f32_16x16x32_bf16(a0, b, acc[c * 4 + nt], 0, 0, 0);
            }
        }
    }
#pragma unroll
    for (int j = 0; j < NCH * 4; ++j) {
        float bc = bias[j * 16 + l16];
#pragma unroll
        for (int r = 0; r < 4; ++r) {
            int row = wave * 16 + q * 4 + r;
            float val = acc[j][r] + bc;
            if (SILU) val = silu_f(val);
            actS[row * ALD + dstCol + j * 16 + l16] = (__bf16)val;
        }
    }
}

__global__ __launch_bounds__(512, 1) void node_chain(
    const __bf16* __restrict__ v, const float* __restrict__ oh,
    const __bf16* __restrict__ w1T, const float* __restrict__ b1,
    const __bf16* __restrict__ w2T, const float* __restrict__ b2,
    const __bf16* __restrict__ wcatT, const float* __restrict__ bcat,
    const __bf16* __restrict__ wupT, const float* __restrict__ bup,
    const __bf16* __restrict__ wl0T, const float* __restrict__ bl0,
    const __bf16* __restrict__ wl1T, const float* __restrict__ bl1,
    const float* __restrict__ wout, float* __restrict__ out, int M) {
    __shared__ __bf16 actS[128 * ALD];  // 100,352 B
    __shared__ __bf16 bS[64 * BLD];     //  50,176 B
    int t = threadIdx.x, wave = t >> 6, lane = t & 63;
    int m0b = blockIdx.x * 128;

    {   // initial load (wave-owned rows): v -> [0,128), oh (f32) -> [256,384)
        int row = wave * 16 + (lane >> 2), quarter = lane & 3;
        int gr = m0b + row; if (gr >= M) gr = M - 1;
        const v8bf* sv = (const v8bf*)(v + (size_t)gr * 128 + quarter * 32);
        const float* so = oh + (size_t)gr * 128 + quarter * 32;
        v8bf* dv = (v8bf*)(actS + row * ALD + quarter * 32);
        v8bf* doh = (v8bf*)(actS + row * ALD + 256 + quarter * 32);
#pragma unroll
        for (int i = 0; i < 4; ++i) { dv[i] = sv[i]; doh[i] = load8f(so + i * 8); }
    }
    // no actS barrier needed (wave-private rows); bS barriers inside gemm_stage

    gemm_stage<128, 2, true >(w1T,   b1,   actS, bS, 256, 128, wave, lane, t);
    gemm_stage<128, 4, false>(w2T,   b2,   actS, bS, 128, 128, wave, lane, t);
    gemm_stage<384, 2, true >(wcatT, bcat, actS, bS, 0,   0,   wave, lane, t);
    gemm_stage<128, 4, false>(wupT,  bup,  actS, bS, 0,   128, wave, lane, t);
    gemm_stage<256, 4, true >(wl0T,  bl0,  actS, bS, 128, 128, wave, lane, t);
    gemm_stage<256, 4, true >(wl1T,  bl1,  actS, bS, 128, 128, wave, lane, t);

    {   // out = a @ w_out (K=256 dot per row, 4 lanes/row)
        int row = wave * 16 + (lane >> 2), quarter = lane & 3;
        const __bf16* ap = actS + row * ALD + 128 + quarter * 64;
        const float* wq = wout + quarter * 64;
        float s = 0.f;
#pragma unroll
        for (int c8 = 0; c8 < 8; ++c8) {
            v8bf a8 = *(const v8bf*)(ap + c8 * 8);
            const float4 w0 = ((const float4*)(wq + c8 * 8))[0];
            const float4 w1 = ((const float4*)(wq + c8 * 8))[1];
            s += (float)a8[0] * w0.x + (float)a8[1] * w0.y + (float)a8[2] * w0.z + (float)a8[3] * w0.w;
            s += (float)a8[4] * w1.x + (float)a8[5] * w1.y + (float)a8[6] * w1.z + (float)a8[7] * w1.w;
        }
        s += __shfl_xor(s, 1);
        s += __shfl_xor(s, 2);
        int gr = m0b + row;
        if (quarter == 0 && gr < M) out[gr] = s;
    }
}

static inline char* align16(char* p) {
    return (char*)(((uintptr_t)p + 15) & ~(uintptr_t)15);
}

extern "C" void kernel_launch(void* const* d_in, const int* in_sizes, int n_in,
                              void* d_out, int out_size, void* d_ws, size_t ws_size,
                              hipStream_t stream) {
    const float* e2      = (const float*)d_in[0];
    const int*   iidx    = (const int*)d_in[1];
    const float* fea     = (const float*)d_in[2];
    const int*   eih     = (const int*)d_in[3];
    const float* w_hull  = (const float*)d_in[4];
    const float* w_mlp0  = (const float*)d_in[5];
    const float* b_mlp0  = (const float*)d_in[6];
    const float* w_mlp1  = (const float*)d_in[7];
    const float* b_mlp1  = (const float*)d_in[8];
    const float* w1_hull = (const float*)d_in[9];
    const float* b1_hull = (const float*)d_in[10];
    const float* w2_hull = (const float*)d_in[11];
    const float* b2_hull = (const float*)d_in[12];
    const float* w_cat   = (const float*)d_in[13];
    const float* b_cat   = (const float*)d_in[14];
    const float* w_up    = (const float*)d_in[15];
    const float* b_up    = (const float*)d_in[16];
    const float* w_l0    = (const float*)d_in[17];
    const float* b_l0    = (const float*)d_in[18];
    const float* w_l1    = (const float*)d_in[19];
    const float* b_l1    = (const float*)d_in[20];
    const float* w_out   = (const float*)d_in[21];

    int N  = out_size;
    int E  = in_sizes[0] / 128;
    int EH = in_sizes[2] / 16;
    const int* jidx_h = eih;           // j_ = row 0
    const int* iidx_h = eih + EH;      // i_ = row 1 (scatter destination)

    char* p = (char*)d_ws;
    __bf16* v     = (__bf16*)p; p += (size_t)N * 128 * 2;
    __bf16* vhull = (__bf16*)p; p += (size_t)N * 128 * 2;
    float*  oh32  = (float*)p;  p += (size_t)N * 128 * 4;
    __bf16* wp = (__bf16*)p;
    __bf16* w_hullT = wp; wp += 128 * 128;
    __bf16* w0T     = wp; wp += 128 * 16;
    __bf16* w1mT    = wp; wp += 128 * 128;
    __bf16* w1hT    = wp; wp += 128 * 128;
    __bf16* w2hT    = wp; wp += 256 * 128;
    __bf16* wcatT   = wp; wp += 128 * 384;
    __bf16* wupT    = wp; wp += 256 * 128;
    __bf16* wl0T    = wp; wp += 256 * 256;
    __bf16* wl1T    = wp; wp += 256 * 256;
    p = align16((char*)wp);
    int* counts   = (int*)p; p += (size_t)N * 4 * 2;   // counts + counts2 (adjacent)
    int* row_s    = (int*)p; p += (size_t)(N + 1) * 4;
    int* cursor   = (int*)p; p += (size_t)N * 4;
    int* row2     = (int*)p; p += (size_t)(N + 1) * 4;
    int* cursor2  = (int*)p; p += (size_t)N * 4;
    int* order    = (int*)p; p += (size_t)E * 4;
    int* perm2    = (int*)p; p += (size_t)EH * 4;
    int* dests2   = (int*)p; p += (size_t)EH * 4;
    int* partials = (int*)p; p += 512 * 4;
    int* counts2  = counts + N;

    TPack tp;
    tp.t[0] = { w_hull,  w_hullT, 128, 128 };
    tp.t[1] = { w_mlp0,  w0T,      16, 128 };
    tp.t[2] = { w_mlp1,  w1mT,    128, 128 };
    tp.t[3] = { w1_hull, w1hT,    128, 128 };
    tp.t[4] = { w2_hull, w2hT,    128, 256 };
    tp.t[5] = { w_cat,   wcatT,   384, 128 };
    tp.t[6] = { w_up,    wupT,    128, 256 };
    tp.t[7] = { w_l0,    wl0T,    256, 256 };
    tp.t[8] = { w_l1,    wl1T,    256, 256 };
    transpose_all<<<dim3(9, 16), 256, 0, stream>>>(tp);

    (void)hipMemsetAsync(counts, 0, (size_t)N * 4 * 2, stream);
    (void)hipMemsetAsync(oh32, 0, (size_t)N * 128 * 4, stream);

    const int nbS = (N + 2047) / 2048;

    // ---- both CSRs in one merged pipeline ----
    hist_both<<<(E + EH + 255) / 256, 256, 0, stream>>>(iidx, iidx_h, counts, counts2, E, EH);
    scan_block_sums<<<2 * nbS, 256, 0, stream>>>(counts, partials, N, nbS);
    scan_partials_two<<<1, 128, 0, stream>>>(partials, nbS, row_s, row2, N, E, EH);
    scan_write<<<2 * nbS, 256, 0, stream>>>(counts, partials, row_s, cursor, row2, cursor2, N, nbS);
    rank_scatter_both<<<(E + EH + 255) / 256, 256, 0, stream>>>(iidx, iidx_h, cursor, cursor2,
                                                                order, perm2, dests2, E, EH);

    gather_v<<<(N + 1) / 2, 256, 0, stream>>>(e2, order, row_s, v, N);

    gemm_vhull<<<(N + 127) / 128, 256, 0, stream>>>(v, w_hullT, vhull, N);

    hull_msg<<<(EH + 63) / 64, 256, 0, stream>>>(fea, perm2, jidx_h, dests2, w0T, b_mlp0,
                                                 w1mT, b_mlp1, vhull, oh32, EH);

    node_chain<<<(N + 127) / 128, 512, 0, stream>>>(v, oh32, w1hT, b1_hull, w2hT, b2_hull,
                                                    wcatT, b_cat, wupT, b_up,
                                                    wl0T, b_l0, wl1T, b_l1,
                                                    w_out, (float*)d_out, N);
}